// Round 1
// 727.288 us; speedup vs baseline: 1.0676x; 1.0676x over previous
//
#include <hip/hip_runtime.h>
#include <hip/hip_bf16.h>

// Cutie memory read: sim = (-mk^2·qe + 2·mk·qk·qe - qe·qk^2)·ms/sqrt(64),
// affinity = softmax_n(sim), out = value @ affinity.
// qe>=0 -> sim <= 0 -> exp(sim) <= 1: no max pass; store es=exp(sim),
// normalize by per-p sum at the end.
// Inputs fp32 (proven R1 vs R2), output fp32.
// R6: gemm_big re-tiled 256x256 (512 thr, 8 waves, 128 KB dbuf LDS, split-K 6)
//     -> staging traffic 2.08 GB -> 1.15 GB, per-K-step working set ~2.5 MB
//     fits per-XCD L2. Swizzle + single-barrier prefetch pipeline kept.
// R7: gemm_big XCD-chunked block swizzle (bijective m204). 1D grid of 252;
//     each XCD owns ~32 consecutive wg (vt fastest, pt, s slowest) so blocks
//     sharing val/es panels share one per-XCD L2. Predict FETCH 788->~300 MB.

#define NTOT 25920   // memory elements (16*30*54)
#define PTOT 1620    // query pixels (30*54)
#define VTOT 1536    // O*CV = 3*512
#define PPAD 1664    // 13*128 (sim grid padding)
#define PPAD2 1792   // 7*256  (gemm p padding; es has this many rows)
#define NPAD 25984   // 203*128
#define KF   128     // packed feature dim (2*CK)
#define SPLITS 6

typedef __hip_bfloat16 bf16;
using frag  = __attribute__((ext_vector_type(8))) short;   // 8 bf16 = 4 VGPR
using f32x4 = __attribute__((ext_vector_type(4))) float;

#define GLOBAL_AS __attribute__((address_space(1)))
#define LDS_AS    __attribute__((address_space(3)))
__device__ __forceinline__ void async_copy16(void* l, const void* g) {
    // per-lane 16B global chunk -> LDS at (wave-uniform base) + lane*16
    __builtin_amdgcn_global_load_lds((const GLOBAL_AS void*)g, (LDS_AS void*)l,
                                     16, 0, 0);
}

// ---------------- ws layout (bytes) ----------------
#define OFF_FLAG ((size_t)0)                    // u32 dtype flag (64 B reserved)
#define OFF_QF   ((size_t)64)                   // bf16 [PPAD][KF]
#define OFF_NF   ((size_t)426048)               // bf16 [NPAD][KF]
#define OFF_BSQ  ((size_t)7077952)              // f32  [PPAD]
#define OFF_MSC  ((size_t)7084608)              // f32  [NPAD]
#define OFF_SUM  ((size_t)7188544)              // f32  [PPAD]
#define OFF_ACC  ((size_t)7195200)              // f32  [VTOT][PTOT]
#define OFF_ES   ((size_t)17148480)             // bf16 [PPAD2][NTOT] 92,897,280 B
#define OFF_VALB ((size_t)110045760)            // bf16 [VTOT][NTOT]  79,626,240 B
#define NEED_BIG ((size_t)189672000)

// ---- dtype detector (bf16 N(0,1) never has exponent >= 0x8F)
__global__ void detect_dtype(const unsigned short* __restrict__ mk16,
                             unsigned* __restrict__ flag) {
    int i = threadIdx.x;            // 32 threads, parallel loads
    unsigned e = (mk16[2 * i] >> 7) & 0xFFu;
    unsigned long long bad = __ballot(e >= 0x8Fu);
    if (i == 0) *flag = bad ? 1u : 0u;   // 1 = fp32 inputs, 0 = bf16 inputs
}

__device__ __forceinline__ float load_in(const void* p, int idx, bool f32) {
    return f32 ? ((const float*)p)[idx]
               : __bfloat162float(((const bf16*)p)[idx]);
}

// ---- pass 0a: qf[p][c]=-qe, qf[p][64+c]=2*qk*qe; bsq; zero sums
__global__ __launch_bounds__(256) void prep_q(const void* __restrict__ key,
                                              const void* __restrict__ sel,
                                              bf16* __restrict__ qf,
                                              float* __restrict__ bsq,
                                              float* __restrict__ sums,
                                              const unsigned* __restrict__ flag) {
    const bool f32 = (*flag != 0u);
    int p = blockIdx.x * 256 + threadIdx.x;
    if (p >= PPAD) return;
    float acc = 0.f;
    for (int c = 0; c < 64; ++c) {
        float qk = 0.f, qe = 0.f;
        if (p < PTOT) {
            qk = load_in(key, c * PTOT + p, f32);
            qe = load_in(sel, c * PTOT + p, f32);
        }
        qf[p * KF + c]      = __float2bfloat16(-qe);
        qf[p * KF + 64 + c] = __float2bfloat16(2.f * qk * qe);
        acc += qe * qk * qk;
    }
    bsq[p]  = acc;
    sums[p] = 0.f;
}

// ---- pass 0b: nf[n][c]=mk^2, nf[n][64+c]=mk; msc=ms/8
__global__ __launch_bounds__(256) void prep_n(const void* __restrict__ mkey,
                                              const void* __restrict__ shr,
                                              bf16* __restrict__ nf,
                                              float* __restrict__ msc,
                                              const unsigned* __restrict__ flag) {
    const bool f32 = (*flag != 0u);
    int n = blockIdx.x * 256 + threadIdx.x;
    if (n >= NPAD) return;
    for (int c = 0; c < 64; ++c) {
        float mk = (n < NTOT) ? load_in(mkey, c * NTOT + n, f32) : 0.f;
        nf[n * KF + c]      = __float2bfloat16(mk * mk);
        nf[n * KF + 64 + c] = __float2bfloat16(mk);
    }
    msc[n] = (n < NTOT) ? load_in(shr, n, f32) * 0.125f : 0.f;
}

// ---- pass 0c (big path): val -> bf16, 8 elements per thread
__global__ __launch_bounds__(256) void conv_val(const void* __restrict__ val,
                                                bf16* __restrict__ valb,
                                                const unsigned* __restrict__ flag) {
    const bool f32 = (*flag != 0u);
    size_t base = ((size_t)blockIdx.x * 256 + threadIdx.x) * 8;
    if (base >= (size_t)VTOT * NTOT) return;
    if (f32) {
        const float4 v0 = *(const float4*)((const float*)val + base);
        const float4 v1 = *(const float4*)((const float*)val + base + 4);
        bf16 o[8] = {__float2bfloat16(v0.x), __float2bfloat16(v0.y),
                     __float2bfloat16(v0.z), __float2bfloat16(v0.w),
                     __float2bfloat16(v1.x), __float2bfloat16(v1.y),
                     __float2bfloat16(v1.z), __float2bfloat16(v1.w)};
        *(uint4*)(valb + base) = *(const uint4*)o;
    } else {
        *(uint4*)(valb + base) = *(const uint4*)((const bf16*)val + base);
    }
}

// ---- pass 1: sim GEMM (p-tile 128 x n-tile 128, K=128) + exp + row sums
// Swizzled LDS: 16B chunk c of row r stored at chunk position c ^ (r&15).
#define EST_LD 136   // shorts; 272 B row stride, 16B-aligned
__global__ __launch_bounds__(256) void sim_kernel(const bf16* __restrict__ qf,
                                                  const bf16* __restrict__ nf,
                                                  const float* __restrict__ bsq,
                                                  const float* __restrict__ msc,
                                                  float* __restrict__ sums,
                                                  bf16* __restrict__ es) {
    __shared__ __align__(16) char smem[65536];
    short* As  = (short*)smem;            // [128][KF] swizzled
    short* Bs  = (short*)(smem + 32768);  // [128][KF] swizzled
    short* Est = (short*)smem;            // [128][EST_LD] (aliases As/Bs)

    const int tid = threadIdx.x;
    const int nt = blockIdx.x, pt = blockIdx.y;
    const int p0 = pt * 128, n0 = nt * 128;
    const int w = tid >> 6, lane = tid & 63;

    // async stage with source-side swizzle: rows are 256 B = 16 chunks
    for (int it = 0; it < 8; ++it) {
        int rb = it * 16 + w * 4;
        int r  = rb + (lane >> 4);
        int cg = (lane & 15) ^ (r & 15);
        async_copy16(&As[rb * KF], qf + (size_t)(p0 + r) * KF + cg * 8);
    }
    for (int it = 0; it < 8; ++it) {
        int rb = it * 16 + w * 4;
        int r  = rb + (lane >> 4);
        int cg = (lane & 15) ^ (r & 15);
        async_copy16(&Bs[rb * KF], nf + (size_t)(n0 + r) * KF + cg * 8);
    }
    __syncthreads();

    const int low = lane & 15, quad = lane >> 4;
    const int wr = w >> 1, wc = w & 1;

    f32x4 acc[4][4] = {};
    for (int kk = 0; kk < 4; ++kk) {
        frag a[4], b[4];
        for (int i = 0; i < 4; ++i) {
            int row = wr * 64 + i * 16 + low;          // row & 15 == low
            a[i] = *(const frag*)&As[row * KF + (((kk * 4 + quad) ^ low) * 8)];
        }
        for (int j = 0; j < 4; ++j) {
            int row = wc * 64 + j * 16 + low;
            b[j] = *(const frag*)&Bs[row * KF + (((kk * 4 + quad) ^ low) * 8)];
        }
        for (int i = 0; i < 4; ++i)
            for (int j = 0; j < 4; ++j)
                acc[i][j] = __builtin_amdgcn_mfma_f32_16x16x32_bf16(a[i], b[j], acc[i][j], 0, 0, 0);
    }

    float msv[4];
    for (int j = 0; j < 4; ++j) msv[j] = msc[n0 + wc * 64 + j * 16 + low];
    __syncthreads();   // all fragment reads done before Est overwrites As/Bs

    for (int i = 0; i < 4; ++i) {
        const int prow = p0 + wr * 64 + i * 16 + quad * 4;
        const float4 bq = *(const float4*)(bsq + prow);
        const float bs[4] = {bq.x, bq.y, bq.z, bq.w};
        for (int r = 0; r < 4; ++r) {
            const int p = prow + r;
            const int rloc = wr * 64 + i * 16 + quad * 4 + r;
            float vsum = 0.f;
            for (int j = 0; j < 4; ++j) {
                const int n = n0 + wc * 64 + j * 16 + low;
                float e = 0.f;
                if (n < NTOT) e = __expf((acc[i][j][r] - bs[r]) * msv[j]);
                vsum += e;
                Est[rloc * EST_LD + wc * 64 + j * 16 + low] = __bfloat16_as_short(__float2bfloat16(e));
            }
            vsum += __shfl_xor(vsum, 1);
            vsum += __shfl_xor(vsum, 2);
            vsum += __shfl_xor(vsum, 4);
            vsum += __shfl_xor(vsum, 8);
            if (p < PTOT && low == 0) atomicAdd(&sums[p], vsum);
        }
    }
    __syncthreads();

    // vectorized store: thread -> (row, half); 8 x uint4 per thread
    const int row = tid >> 1, half = tid & 1;
    const int p = p0 + row;
    if (p < PTOT) {
        bf16* dst = es + (size_t)p * NTOT + n0 + half * 64;
        const short* src = Est + row * EST_LD + half * 64;
        for (int m = 0; m < 8; ++m) {
            int ng = n0 + half * 64 + m * 8;
            if (ng + 8 <= NTOT)
                *(uint4*)(dst + m * 8) = *(const uint4*)(src + m * 8);
        }
    }
}

// ---- pass 2a (big): 256x256 readout GEMM, prefetch pipeline + swizzle
// R7: 1D grid (252 blocks), XCD-chunked bijective swizzle. Blocks sharing
// val panels (same vt,s) and es panels (same pt,s) land on one XCD's L2.
__global__ __launch_bounds__(512) void gemm_big(const bf16* __restrict__ val,
                                                const bf16* __restrict__ es,
                                                float* __restrict__ accb) {
    // double-buffered: [2][256][64] each, swizzled (chunk c at c ^ (r&7))
    __shared__ __align__(16) short As[2][256 * 64];   // v rows
    __shared__ __align__(16) short Bs[2][256 * 64];   // p rows
    const int tid = threadIdx.x;

    // bijective XCD chunking (m204): consecutive orig ids round-robin XCDs,
    // so orig%8 == XCD; give each XCD a contiguous chunk of wg space.
    const int nwg = (PPAD2 / 256) * (VTOT / 256) * SPLITS;   // 252
    const int orig = blockIdx.x;
    const int xcd = orig & 7;
    const int q = nwg >> 3, r8 = nwg & 7;                    // 31, 4
    const int cbase = (xcd < r8) ? xcd * (q + 1) : r8 * (q + 1) + (xcd - r8) * q;
    const int wg = cbase + (orig >> 3);
    // vt fastest (es panel groups contiguous), then pt, then s slowest:
    // one XCD chunk = one s-slab, all vt, ~5 pt values.
    const int vt = wg % 6;
    const int t2 = wg / 6;
    const int pt = t2 % 7;
    const int s  = t2 / 7;

    const int p0 = pt * 256, v0 = vt * 256;
    const int ks = s * 68;
    const int ke = (ks + 68 < 405) ? ks + 68 : 405;

    const int w = tid >> 6, lane = tid & 63, low = lane & 15, quad = lane >> 4;
    const int wv = w >> 1, wp = w & 1;     // wv: v quarter (64), wp: p half (128)
    const int rA = lane >> 3;              // 0..7 within 8-row group
    const int cgx = (lane & 7) ^ rA;       // swizzled source chunk (rb%8==0)

    // stage tile kt into buffer b: 8 global_load_lds per wave (4 A + 4 B)
    auto stage = [&](int kt, int b) {
        const int k0 = kt * 64;
#pragma unroll
        for (int it = 0; it < 4; ++it) {
            int rb = it * 64 + w * 8;
            async_copy16(&As[b][rb * 64],
                         val + (size_t)(v0 + rb + rA) * NTOT + k0 + cgx * 8);
        }
#pragma unroll
        for (int it = 0; it < 4; ++it) {
            int rb = it * 64 + w * 8;
            async_copy16(&Bs[b][rb * 64],
                         es + (size_t)(p0 + rb + rA) * NTOT + k0 + cgx * 8);
        }
    };

    f32x4 acc[4][8] = {};
    stage(ks, 0);
    int buf = 0;
    for (int kt = ks; kt < ke; ++kt) {
        __builtin_amdgcn_s_waitcnt(0);     // this wave's copies for tile kt done
        __builtin_amdgcn_s_barrier();      // all waves: kt staged, kt-1 consumed
        if (kt + 1 < ke) stage(kt + 1, buf ^ 1);
        const short* A = As[buf];
        const short* B = Bs[buf];
#pragma unroll
        for (int kk = 0; kk < 2; ++kk) {
            frag a[4], b[8];
            for (int i = 0; i < 4; ++i) {
                int row = wv * 64 + i * 16 + low;   // row & 7 == low & 7
                a[i] = *(const frag*)&A[row * 64 + (((kk * 4 + quad) ^ (low & 7)) * 8)];
            }
            for (int j = 0; j < 8; ++j) {
                int row = wp * 128 + j * 16 + low;
                b[j] = *(const frag*)&B[row * 64 + (((kk * 4 + quad) ^ (low & 7)) * 8)];
            }
            for (int i = 0; i < 4; ++i)
                for (int j = 0; j < 8; ++j)
                    acc[i][j] = __builtin_amdgcn_mfma_f32_16x16x32_bf16(a[i], b[j], acc[i][j], 0, 0, 0);
        }
        buf ^= 1;
    }

    for (int i = 0; i < 4; ++i)
        for (int r = 0; r < 4; ++r) {
            const int v = v0 + wv * 64 + i * 16 + quad * 4 + r;
            for (int j = 0; j < 8; ++j) {
                const int p = p0 + wp * 128 + j * 16 + low;
                if (p < PTOT) atomicAdd(&accb[(size_t)v * PTOT + p], acc[i][j][r]);
            }
        }
}

// ---- pass 2b (small ws): fallback readout GEMM (128-tiles, unswizzled)
__global__ __launch_bounds__(256) void gemm_small(const void* __restrict__ val,
                                                  const bf16* __restrict__ es,
                                                  float* __restrict__ accb,
                                                  const unsigned* __restrict__ flag) {
    __shared__ short As[128 * 64];
    __shared__ short Bs[128 * 64];
    const bool f32 = (*flag != 0u);
    const int tid = threadIdx.x;
    const int pt = blockIdx.x, vt = blockIdx.y, s = blockIdx.z;
    const int p0 = pt * 128, v0 = vt * 128;
    const int ks = s * 51;
    const int ke = (ks + 51 < 405) ? ks + 51 : 405;

    const int w = tid >> 6, lane = tid & 63, low = lane & 15, quad = lane >> 4;
    const int wr = w >> 1, wc = w & 1;

    f32x4 acc[4][4] = {};
    for (int kt = ks; kt < ke; ++kt) {
        const int k0 = kt * 64;
        if (f32) {
            for (int it = 0; it < 8; ++it) {
                int ci = it * 256 + tid, row = ci >> 4, c4 = ci & 15;
                const float4 v = *(const float4*)((const float*)val +
                                  (size_t)(v0 + row) * NTOT + k0 + c4 * 4);
                bf16 o[4] = {__float2bfloat16(v.x), __float2bfloat16(v.y),
                             __float2bfloat16(v.z), __float2bfloat16(v.w)};
                *(uint2*)&As[row * 64 + c4 * 4] = *(const uint2*)o;
            }
        } else {
            for (int it = 0; it < 4; ++it) {
                int ci = it * 256 + tid, row = ci >> 3, c8 = ci & 7;
                ((uint4*)As)[ci] = *(const uint4*)((const bf16*)val +
                                   (size_t)(v0 + row) * NTOT + k0 + c8 * 8);
            }
        }
        for (int it = 0; it < 4; ++it) {
            int ci = it * 256 + tid, row = ci >> 3, c8 = ci & 7;
            ((uint4*)Bs)[ci] = *(const uint4*)(es + (size_t)(p0 + row) * NTOT + k0 + c8 * 8);
        }
        __syncthreads();
        for (int kk = 0; kk < 2; ++kk) {
            frag a[4], b[4];
            for (int i = 0; i < 4; ++i)
                a[i] = *(const frag*)&As[(wr * 64 + i * 16 + low) * 64 + kk * 32 + quad * 8];
            for (int j = 0; j < 4; ++j)
                b[j] = *(const frag*)&Bs[(wc * 64 + j * 16 + low) * 64 + kk * 32 + quad * 8];
            for (int i = 0; i < 4; ++i)
                for (int j = 0; j < 4; ++j)
                    acc[i][j] = __builtin_amdgcn_mfma_f32_16x16x32_bf16(a[i], b[j], acc[i][j], 0, 0, 0);
        }
        __syncthreads();
    }

    for (int i = 0; i < 4; ++i)
        for (int r = 0; r < 4; ++r) {
            const int v = v0 + wr * 64 + i * 16 + quad * 4 + r;
            for (int j = 0; j < 4; ++j) {
                const int p = p0 + wc * 64 + j * 16 + low;
                if (p < PTOT) atomicAdd(&accb[(size_t)v * PTOT + p], acc[i][j][r]);
            }
        }
}

// ---- pass 3: normalize; output fp32
__global__ __launch_bounds__(256) void finalize(const float* __restrict__ accb,
                                                const float* __restrict__ sums,
                                                float* __restrict__ out) {
    int i = blockIdx.x * 256 + threadIdx.x;
    if (i < VTOT * PTOT) {
        int p = i % PTOT;
        out[i] = accb[i] / sums[p];
    }
}

extern "C" void kernel_launch(void* const* d_in, const int* in_sizes, int n_in,
                              void* d_out, int out_size, void* d_ws, size_t ws_size,
                              hipStream_t stream) {
    const void* mkey = d_in[0];   // memory_key        [64][25920]
    const void* shr  = d_in[1];   // memory_shrinkage  [25920]
    const void* key  = d_in[2];   // key               [64][1620]
    const void* sel  = d_in[3];   // selection         [64][1620]
    const void* val  = d_in[4];   // memory_mask_value [1536][25920]
    float* out = (float*)d_out;

    char* ws = (char*)d_ws;
    unsigned* flag = (unsigned*)(ws + OFF_FLAG);
    bf16*  qf   = (bf16*)(ws + OFF_QF);
    bf16*  nf   = (bf16*)(ws + OFF_NF);
    float* bsq  = (float*)(ws + OFF_BSQ);
    float* msc  = (float*)(ws + OFF_MSC);
    float* sums = (float*)(ws + OFF_SUM);
    float* accb = (float*)(ws + OFF_ACC);
    bf16*  es   = (bf16*)(ws + OFF_ES);
    bf16*  valb = (bf16*)(ws + OFF_VALB);

    detect_dtype<<<1, 32, 0, stream>>>((const unsigned short*)mkey, flag);
    hipMemsetAsync(accb, 0, (size_t)VTOT * PTOT * sizeof(float), stream);
    prep_q<<<(PPAD + 255) / 256, 256, 0, stream>>>(key, sel, qf, bsq, sums, flag);
    prep_n<<<(NPAD + 255) / 256, 256, 0, stream>>>(mkey, shr, nf, msc, flag);
    sim_kernel<<<dim3(NPAD / 128, PPAD / 128), 256, 0, stream>>>(qf, nf, bsq, msc, sums, es);
    if (ws_size >= NEED_BIG) {
        size_t nv = (size_t)VTOT * NTOT;
        conv_val<<<(unsigned)((nv / 8 + 255) / 256), 256, 0, stream>>>(val, valb, flag);
        gemm_big<<<dim3((PPAD2 / 256) * (VTOT / 256) * SPLITS), 512, 0, stream>>>(valb, es, accb);
    } else {
        gemm_small<<<dim3(PPAD / 128, VTOT / 128, 8), 256, 0, stream>>>(val, es, accb, flag);
    }
    finalize<<<(VTOT * PTOT + 255) / 256, 256, 0, stream>>>(accb, sums, out);
}

// Round 3
// 676.909 us; speedup vs baseline: 1.1471x; 1.0744x over previous
//
#include <hip/hip_runtime.h>
#include <hip/hip_bf16.h>

// Cutie memory read: sim = (-mk^2·qe + 2·mk·qk·qe - qe·qk^2)·ms/sqrt(64),
// affinity = softmax_n(sim), out = value @ affinity.
// qe>=0 -> sim <= 0 -> exp(sim) <= 1: no max pass; store es=exp(sim),
// normalize by per-p sum at the end.
// R6: gemm_big 256x256 (512 thr, 8 waves, 128 KB dbuf LDS, split-K 6).
// R7: XCD-chunked bijective block swizzle: FETCH 788->134 MB (proven).
// R8: gemm_big 4 phases/K-tile, half-tile staging, counted vmcnt, raw
//     s_barrier, setprio. RACE in tail: when stageB(t+2) skipped, vmcnt(4)
//     left A(t+1) in flight -> last tile read unlanded LDS.
// R9: exact tail wait: vmcnt(4) while t+2<ke else vmcnt(0). Ledger:
//     steady q3 outstanding = B(t+1)4 + A(t+1)4 + B(t+2)4; vmcnt(4) drains
//     B(t+1),A(t+1). Tail (B(t+2) skipped): vmcnt(0) drains both.

#define NTOT 25920   // memory elements (16*30*54)
#define PTOT 1620    // query pixels (30*54)
#define VTOT 1536    // O*CV = 3*512
#define PPAD 1664    // 13*128 (sim grid padding)
#define PPAD2 1792   // 7*256  (gemm p padding; es has this many rows)
#define NPAD 25984   // 203*128
#define KF   128     // packed feature dim (2*CK)
#define SPLITS 6

typedef __hip_bfloat16 bf16;
using frag  = __attribute__((ext_vector_type(8))) short;   // 8 bf16 = 4 VGPR
using f32x4 = __attribute__((ext_vector_type(4))) float;

#define GLOBAL_AS __attribute__((address_space(1)))
#define LDS_AS    __attribute__((address_space(3)))
__device__ __forceinline__ void async_copy16(void* l, const void* g) {
    // per-lane 16B global chunk -> LDS at (wave-uniform base) + lane*16
    __builtin_amdgcn_global_load_lds((const GLOBAL_AS void*)g, (LDS_AS void*)l,
                                     16, 0, 0);
}

// ---------------- ws layout (bytes) ----------------
#define OFF_FLAG ((size_t)0)                    // u32 dtype flag (64 B reserved)
#define OFF_QF   ((size_t)64)                   // bf16 [PPAD][KF]
#define OFF_NF   ((size_t)426048)               // bf16 [NPAD][KF]
#define OFF_BSQ  ((size_t)7077952)              // f32  [PPAD]
#define OFF_MSC  ((size_t)7084608)              // f32  [NPAD]
#define OFF_SUM  ((size_t)7188544)              // f32  [PPAD]
#define OFF_ACC  ((size_t)7195200)              // f32  [VTOT][PTOT]
#define OFF_ES   ((size_t)17148480)             // bf16 [PPAD2][NTOT] 92,897,280 B
#define OFF_VALB ((size_t)110045760)            // bf16 [VTOT][NTOT]  79,626,240 B
#define NEED_BIG ((size_t)189672000)

// ---- dtype detector (bf16 N(0,1) never has exponent >= 0x8F)
__global__ void detect_dtype(const unsigned short* __restrict__ mk16,
                             unsigned* __restrict__ flag) {
    int i = threadIdx.x;            // 32 threads, parallel loads
    unsigned e = (mk16[2 * i] >> 7) & 0xFFu;
    unsigned long long bad = __ballot(e >= 0x8Fu);
    if (i == 0) *flag = bad ? 1u : 0u;   // 1 = fp32 inputs, 0 = bf16 inputs
}

__device__ __forceinline__ float load_in(const void* p, int idx, bool f32) {
    return f32 ? ((const float*)p)[idx]
               : __bfloat162float(((const bf16*)p)[idx]);
}

// ---- pass 0a: qf[p][c]=-qe, qf[p][64+c]=2*qk*qe; bsq; zero sums
__global__ __launch_bounds__(256) void prep_q(const void* __restrict__ key,
                                              const void* __restrict__ sel,
                                              bf16* __restrict__ qf,
                                              float* __restrict__ bsq,
                                              float* __restrict__ sums,
                                              const unsigned* __restrict__ flag) {
    const bool f32 = (*flag != 0u);
    int p = blockIdx.x * 256 + threadIdx.x;
    if (p >= PPAD) return;
    float acc = 0.f;
    for (int c = 0; c < 64; ++c) {
        float qk = 0.f, qe = 0.f;
        if (p < PTOT) {
            qk = load_in(key, c * PTOT + p, f32);
            qe = load_in(sel, c * PTOT + p, f32);
        }
        qf[p * KF + c]      = __float2bfloat16(-qe);
        qf[p * KF + 64 + c] = __float2bfloat16(2.f * qk * qe);
        acc += qe * qk * qk;
    }
    bsq[p]  = acc;
    sums[p] = 0.f;
}

// ---- pass 0b: nf[n][c]=mk^2, nf[n][64+c]=mk; msc=ms/8
__global__ __launch_bounds__(256) void prep_n(const void* __restrict__ mkey,
                                              const void* __restrict__ shr,
                                              bf16* __restrict__ nf,
                                              float* __restrict__ msc,
                                              const unsigned* __restrict__ flag) {
    const bool f32 = (*flag != 0u);
    int n = blockIdx.x * 256 + threadIdx.x;
    if (n >= NPAD) return;
    for (int c = 0; c < 64; ++c) {
        float mk = (n < NTOT) ? load_in(mkey, c * NTOT + n, f32) : 0.f;
        nf[n * KF + c]      = __float2bfloat16(mk * mk);
        nf[n * KF + 64 + c] = __float2bfloat16(mk);
    }
    msc[n] = (n < NTOT) ? load_in(shr, n, f32) * 0.125f : 0.f;
}

// ---- pass 0c (big path): val -> bf16, 8 elements per thread
__global__ __launch_bounds__(256) void conv_val(const void* __restrict__ val,
                                                bf16* __restrict__ valb,
                                                const unsigned* __restrict__ flag) {
    const bool f32 = (*flag != 0u);
    size_t base = ((size_t)blockIdx.x * 256 + threadIdx.x) * 8;
    if (base >= (size_t)VTOT * NTOT) return;
    if (f32) {
        const float4 v0 = *(const float4*)((const float*)val + base);
        const float4 v1 = *(const float4*)((const float*)val + base + 4);
        bf16 o[8] = {__float2bfloat16(v0.x), __float2bfloat16(v0.y),
                     __float2bfloat16(v0.z), __float2bfloat16(v0.w),
                     __float2bfloat16(v1.x), __float2bfloat16(v1.y),
                     __float2bfloat16(v1.z), __float2bfloat16(v1.w)};
        *(uint4*)(valb + base) = *(const uint4*)o;
    } else {
        *(uint4*)(valb + base) = *(const uint4*)((const bf16*)val + base);
    }
}

// ---- pass 1: sim GEMM (p-tile 128 x n-tile 128, K=128) + exp + row sums
// Swizzled LDS: 16B chunk c of row r stored at chunk position c ^ (r&15).
#define EST_LD 136   // shorts; 272 B row stride, 16B-aligned
__global__ __launch_bounds__(256) void sim_kernel(const bf16* __restrict__ qf,
                                                  const bf16* __restrict__ nf,
                                                  const float* __restrict__ bsq,
                                                  const float* __restrict__ msc,
                                                  float* __restrict__ sums,
                                                  bf16* __restrict__ es) {
    __shared__ __align__(16) char smem[65536];
    short* As  = (short*)smem;            // [128][KF] swizzled
    short* Bs  = (short*)(smem + 32768);  // [128][KF] swizzled
    short* Est = (short*)smem;            // [128][EST_LD] (aliases As/Bs)

    const int tid = threadIdx.x;
    const int nt = blockIdx.x, pt = blockIdx.y;
    const int p0 = pt * 128, n0 = nt * 128;
    const int w = tid >> 6, lane = tid & 63;

    // async stage with source-side swizzle: rows are 256 B = 16 chunks
    for (int it = 0; it < 8; ++it) {
        int rb = it * 16 + w * 4;
        int r  = rb + (lane >> 4);
        int cg = (lane & 15) ^ (r & 15);
        async_copy16(&As[rb * KF], qf + (size_t)(p0 + r) * KF + cg * 8);
    }
    for (int it = 0; it < 8; ++it) {
        int rb = it * 16 + w * 4;
        int r  = rb + (lane >> 4);
        int cg = (lane & 15) ^ (r & 15);
        async_copy16(&Bs[rb * KF], nf + (size_t)(n0 + r) * KF + cg * 8);
    }
    __syncthreads();

    const int low = lane & 15, quad = lane >> 4;
    const int wr = w >> 1, wc = w & 1;

    f32x4 acc[4][4] = {};
    for (int kk = 0; kk < 4; ++kk) {
        frag a[4], b[4];
        for (int i = 0; i < 4; ++i) {
            int row = wr * 64 + i * 16 + low;          // row & 15 == low
            a[i] = *(const frag*)&As[row * KF + (((kk * 4 + quad) ^ low) * 8)];
        }
        for (int j = 0; j < 4; ++j) {
            int row = wc * 64 + j * 16 + low;
            b[j] = *(const frag*)&Bs[row * KF + (((kk * 4 + quad) ^ low) * 8)];
        }
        for (int i = 0; i < 4; ++i)
            for (int j = 0; j < 4; ++j)
                acc[i][j] = __builtin_amdgcn_mfma_f32_16x16x32_bf16(a[i], b[j], acc[i][j], 0, 0, 0);
    }

    float msv[4];
    for (int j = 0; j < 4; ++j) msv[j] = msc[n0 + wc * 64 + j * 16 + low];
    __syncthreads();   // all fragment reads done before Est overwrites As/Bs

    for (int i = 0; i < 4; ++i) {
        const int prow = p0 + wr * 64 + i * 16 + quad * 4;
        const float4 bq = *(const float4*)(bsq + prow);
        const float bs[4] = {bq.x, bq.y, bq.z, bq.w};
        for (int r = 0; r < 4; ++r) {
            const int p = prow + r;
            const int rloc = wr * 64 + i * 16 + quad * 4 + r;
            float vsum = 0.f;
            for (int j = 0; j < 4; ++j) {
                const int n = n0 + wc * 64 + j * 16 + low;
                float e = 0.f;
                if (n < NTOT) e = __expf((acc[i][j][r] - bs[r]) * msv[j]);
                vsum += e;
                Est[rloc * EST_LD + wc * 64 + j * 16 + low] = __bfloat16_as_short(__float2bfloat16(e));
            }
            vsum += __shfl_xor(vsum, 1);
            vsum += __shfl_xor(vsum, 2);
            vsum += __shfl_xor(vsum, 4);
            vsum += __shfl_xor(vsum, 8);
            if (p < PTOT && low == 0) atomicAdd(&sums[p], vsum);
        }
    }
    __syncthreads();

    // vectorized store: thread -> (row, half); 8 x uint4 per thread
    const int row = tid >> 1, half = tid & 1;
    const int p = p0 + row;
    if (p < PTOT) {
        bf16* dst = es + (size_t)p * NTOT + n0 + half * 64;
        const short* src = Est + row * EST_LD + half * 64;
        for (int m = 0; m < 8; ++m) {
            int ng = n0 + half * 64 + m * 8;
            if (ng + 8 <= NTOT)
                *(uint4*)(dst + m * 8) = *(const uint4*)(src + m * 8);
        }
    }
}

// ---- pass 2a (big): 256x256 readout GEMM, 4-phase counted-vmcnt schedule.
// Waves: wv = v-half (128 rows), wp = p-quarter (64 rows). acc[8][4].
// LDS: As[buf][half][128][64], Bs[buf][half][128][64] (swizzled, 128 KB).
// Per K-tile t (buf = t&1), 4 phases:
//   ph0: read all B frags (regs, held whole tile) + A(i=0,1); stage A0(t+1)
//   ph1: read A(i=2,3); stage A1(t+1)
//   ph2: read A(i=4,5); stage B0(t+2)   <- cur B region free after ph0
//   ph3: read A(i=6,7); stage B1(t+2); vmcnt(4 or 0 in tail); barrier
__global__ __launch_bounds__(512) void gemm_big(const bf16* __restrict__ val,
                                                const bf16* __restrict__ es,
                                                float* __restrict__ accb) {
    __shared__ __align__(16) short As[2][2][128 * 64];   // v rows
    __shared__ __align__(16) short Bs[2][2][128 * 64];   // p rows
    const int tid = threadIdx.x;

    // bijective XCD chunking (m204): consecutive orig ids round-robin XCDs.
    const int nwg = (PPAD2 / 256) * (VTOT / 256) * SPLITS;   // 252
    const int orig = blockIdx.x;
    const int xcd = orig & 7;
    const int q8 = nwg >> 3, r8 = nwg & 7;                   // 31, 4
    const int cbase = (xcd < r8) ? xcd * (q8 + 1) : r8 * (q8 + 1) + (xcd - r8) * q8;
    const int wg = cbase + (orig >> 3);
    const int vt = wg % 6;
    const int t2 = wg / 6;
    const int pt = t2 % 7;
    const int s  = t2 / 7;

    const int p0 = pt * 256, v0 = vt * 256;
    const int ks = s * 68;
    const int ke = (ks + 68 < 405) ? ks + 68 : 405;

    const int w = tid >> 6, lane = tid & 63, low = lane & 15, quad = lane >> 4;
    const int wv = w >> 2, wp = w & 3;     // wv: v half (128), wp: p quarter (64)
    const int rA = lane >> 3;              // 0..7 within 8-row group
    const int cgx = (lane & 7) ^ rA;       // swizzled source chunk (rb%8==0)

    // stage one half-tile (128 rows x 64 k) = 2 global_load_lds per wave
    auto stageA = [&](int t, int h) {
        if (t >= ke) return;
        const int k0 = t * 64, bb = t & 1;
#pragma unroll
        for (int it = 0; it < 2; ++it) {
            int rb = it * 64 + w * 8;
            async_copy16(&As[bb][h][rb * 64],
                         val + (size_t)(v0 + h * 128 + rb + rA) * NTOT + k0 + cgx * 8);
        }
    };
    auto stageB = [&](int t, int h) {
        if (t >= ke) return;
        const int k0 = t * 64, bb = t & 1;
#pragma unroll
        for (int it = 0; it < 2; ++it) {
            int rb = it * 64 + w * 8;
            async_copy16(&Bs[bb][h][rb * 64],
                         es + (size_t)(p0 + h * 128 + rb + rA) * NTOT + k0 + cgx * 8);
        }
    };

    const int hB = wp >> 1;                 // this wave's B half
    const int rB0 = (wp & 1) * 64 + low;    // B row-in-half base (+ j*16)
    const int c0 = ((0 * 4 + quad) ^ (low & 7)) * 8;   // kk=0 column (shorts)
    const int c1 = ((1 * 4 + quad) ^ (low & 7)) * 8;   // kk=1 column

    f32x4 acc[8][4] = {};

    // prologue: B(ks), A(ks), B(ks+1); wait A(ks) landed (B(ks+1) in flight)
    stageB(ks, 0); stageB(ks, 1);
    stageA(ks, 0); stageA(ks, 1);
    stageB(ks + 1, 0); stageB(ks + 1, 1);
    asm volatile("s_waitcnt vmcnt(4)" ::: "memory");
    __builtin_amdgcn_s_barrier();

    for (int t = ks; t < ke; ++t) {
        const int bb = t & 1;
        const short* Ab = As[bb][wv];
        const short* Bb = Bs[bb][hB];
        frag bfr[2][4];                      // held in regs across all phases

#pragma unroll
        for (int q = 0; q < 4; ++q) {
            // ---- reads for this phase
            if (q == 0) {
#pragma unroll
                for (int j = 0; j < 4; ++j) {
                    bfr[0][j] = *(const frag*)&Bb[(rB0 + j * 16) * 64 + c0];
                    bfr[1][j] = *(const frag*)&Bb[(rB0 + j * 16) * 64 + c1];
                }
            }
            frag a00, a01, a10, a11;         // i = 2q, 2q+1; kk = 0,1
            {
                const short* r0 = &Ab[((2 * q) * 16 + low) * 64];
                const short* r1 = &Ab[((2 * q + 1) * 16 + low) * 64];
                a00 = *(const frag*)&r0[c0];
                a01 = *(const frag*)&r0[c1];
                a10 = *(const frag*)&r1[c0];
                a11 = *(const frag*)&r1[c1];
            }
            // ---- stage for this phase
            if (q == 0)      stageA(t + 1, 0);
            else if (q == 1) stageA(t + 1, 1);
            else if (q == 2) stageB(t + 2, 0);
            else             stageB(t + 2, 1);

            __builtin_amdgcn_s_barrier();
            asm volatile("s_waitcnt lgkmcnt(0)" ::: "memory");
            __builtin_amdgcn_s_setprio(1);
#pragma unroll
            for (int j = 0; j < 4; ++j) {
                acc[2 * q][j]     = __builtin_amdgcn_mfma_f32_16x16x32_bf16(a00, bfr[0][j], acc[2 * q][j], 0, 0, 0);
                acc[2 * q][j]     = __builtin_amdgcn_mfma_f32_16x16x32_bf16(a01, bfr[1][j], acc[2 * q][j], 0, 0, 0);
                acc[2 * q + 1][j] = __builtin_amdgcn_mfma_f32_16x16x32_bf16(a10, bfr[0][j], acc[2 * q + 1][j], 0, 0, 0);
                acc[2 * q + 1][j] = __builtin_amdgcn_mfma_f32_16x16x32_bf16(a11, bfr[1][j], acc[2 * q + 1][j], 0, 0, 0);
            }
            __builtin_amdgcn_s_setprio(0);
            if (q == 3) {
                // Exact drain ledger (R9 fix): steady state leaves B(t+2)
                // in flight; when B(t+2) was skipped (tail), A(t+1)/B(t+1)
                // would be the newest 4 — must drain fully instead.
                if (t + 2 < ke)
                    asm volatile("s_waitcnt vmcnt(4)" ::: "memory");
                else
                    asm volatile("s_waitcnt vmcnt(0)" ::: "memory");
            }
            __builtin_amdgcn_s_barrier();
        }
    }

    for (int i = 0; i < 8; ++i)
        for (int r = 0; r < 4; ++r) {
            const int v = v0 + wv * 128 + i * 16 + quad * 4 + r;
            for (int j = 0; j < 4; ++j) {
                const int p = p0 + wp * 64 + j * 16 + low;
                if (p < PTOT) atomicAdd(&accb[(size_t)v * PTOT + p], acc[i][j][r]);
            }
        }
}

// ---- pass 2b (small ws): fallback readout GEMM (128-tiles, unswizzled)
__global__ __launch_bounds__(256) void gemm_small(const void* __restrict__ val,
                                                  const bf16* __restrict__ es,
                                                  float* __restrict__ accb,
                                                  const unsigned* __restrict__ flag) {
    __shared__ short As[128 * 64];
    __shared__ short Bs[128 * 64];
    const bool f32 = (*flag != 0u);
    const int tid = threadIdx.x;
    const int pt = blockIdx.x, vt = blockIdx.y, s = blockIdx.z;
    const int p0 = pt * 128, v0 = vt * 128;
    const int ks = s * 51;
    const int ke = (ks + 51 < 405) ? ks + 51 : 405;

    const int w = tid >> 6, lane = tid & 63, low = lane & 15, quad = lane >> 4;
    const int wr = w >> 1, wc = w & 1;

    f32x4 acc[4][4] = {};
    for (int kt = ks; kt < ke; ++kt) {
        const int k0 = kt * 64;
        if (f32) {
            for (int it = 0; it < 8; ++it) {
                int ci = it * 256 + tid, row = ci >> 4, c4 = ci & 15;
                const float4 v = *(const float4*)((const float*)val +
                                  (size_t)(v0 + row) * NTOT + k0 + c4 * 4);
                bf16 o[4] = {__float2bfloat16(v.x), __float2bfloat16(v.y),
                             __float2bfloat16(v.z), __float2bfloat16(v.w)};
                *(uint2*)&As[row * 64 + c4 * 4] = *(const uint2*)o;
            }
        } else {
            for (int it = 0; it < 4; ++it) {
                int ci = it * 256 + tid, row = ci >> 3, c8 = ci & 7;
                ((uint4*)As)[ci] = *(const uint4*)((const bf16*)val +
                                   (size_t)(v0 + row) * NTOT + k0 + c8 * 8);
            }
        }
        for (int it = 0; it < 4; ++it) {
            int ci = it * 256 + tid, row = ci >> 3, c8 = ci & 7;
            ((uint4*)Bs)[ci] = *(const uint4*)(es + (size_t)(p0 + row) * NTOT + k0 + c8 * 8);
        }
        __syncthreads();
        for (int kk = 0; kk < 2; ++kk) {
            frag a[4], b[4];
            for (int i = 0; i < 4; ++i)
                a[i] = *(const frag*)&As[(wr * 64 + i * 16 + low) * 64 + kk * 32 + quad * 8];
            for (int j = 0; j < 4; ++j)
                b[j] = *(const frag*)&Bs[(wc * 64 + j * 16 + low) * 64 + kk * 32 + quad * 8];
            for (int i = 0; i < 4; ++i)
                for (int j = 0; j < 4; ++j)
                    acc[i][j] = __builtin_amdgcn_mfma_f32_16x16x32_bf16(a[i], b[j], acc[i][j], 0, 0, 0);
        }
        __syncthreads();
    }

    for (int i = 0; i < 4; ++i)
        for (int r = 0; r < 4; ++r) {
            const int v = v0 + wr * 64 + i * 16 + quad * 4 + r;
            for (int j = 0; j < 4; ++j) {
                const int p = p0 + wc * 64 + j * 16 + low;
                if (p < PTOT) atomicAdd(&accb[(size_t)v * PTOT + p], acc[i][j][r]);
            }
        }
}

// ---- pass 3: normalize; output fp32
__global__ __launch_bounds__(256) void finalize(const float* __restrict__ accb,
                                                const float* __restrict__ sums,
                                                float* __restrict__ out) {
    int i = blockIdx.x * 256 + threadIdx.x;
    if (i < VTOT * PTOT) {
        int p = i % PTOT;
        out[i] = accb[i] / sums[p];
    }
}

extern "C" void kernel_launch(void* const* d_in, const int* in_sizes, int n_in,
                              void* d_out, int out_size, void* d_ws, size_t ws_size,
                              hipStream_t stream) {
    const void* mkey = d_in[0];   // memory_key        [64][25920]
    const void* shr  = d_in[1];   // memory_shrinkage  [25920]
    const void* key  = d_in[2];   // key               [64][1620]
    const void* sel  = d_in[3];   // selection         [64][1620]
    const void* val  = d_in[4];   // memory_mask_value [1536][25920]
    float* out = (float*)d_out;

    char* ws = (char*)d_ws;
    unsigned* flag = (unsigned*)(ws + OFF_FLAG);
    bf16*  qf   = (bf16*)(ws + OFF_QF);
    bf16*  nf   = (bf16*)(ws + OFF_NF);
    float* bsq  = (float*)(ws + OFF_BSQ);
    float* msc  = (float*)(ws + OFF_MSC);
    float* sums = (float*)(ws + OFF_SUM);
    float* accb = (float*)(ws + OFF_ACC);
    bf16*  es   = (bf16*)(ws + OFF_ES);
    bf16*  valb = (bf16*)(ws + OFF_VALB);

    detect_dtype<<<1, 32, 0, stream>>>((const unsigned short*)mkey, flag);
    hipMemsetAsync(accb, 0, (size_t)VTOT * PTOT * sizeof(float), stream);
    prep_q<<<(PPAD + 255) / 256, 256, 0, stream>>>(key, sel, qf, bsq, sums, flag);
    prep_n<<<(NPAD + 255) / 256, 256, 0, stream>>>(mkey, shr, nf, msc, flag);
    sim_kernel<<<dim3(NPAD / 128, PPAD / 128), 256, 0, stream>>>(qf, nf, bsq, msc, sums, es);
    if (ws_size >= NEED_BIG) {
        size_t nv = (size_t)VTOT * NTOT;
        conv_val<<<(unsigned)((nv / 8 + 255) / 256), 256, 0, stream>>>(val, valb, flag);
        gemm_big<<<dim3((PPAD2 / 256) * (VTOT / 256) * SPLITS), 512, 0, stream>>>(valb, es, accb);
    } else {
        gemm_small<<<dim3(PPAD / 128, VTOT / 128, 8), 256, 0, stream>>>(val, es, accb, flag);
    }
    finalize<<<(VTOT * PTOT + 255) / 256, 256, 0, stream>>>(accb, sums, out);
}